// Round 13
// baseline (844.141 us; speedup 1.0000x reference)
//
#include <hip/hip_runtime.h>
#include <hip/hip_bf16.h>
#include <math.h>

// TemporalTransformerConv (TGAT-like) for MI355X — round 13.
// Round 12's persistent edge kernel, LDS sized CORRECTLY: both B tables are
// 64 KB each -> 128 KB LDS (gfx950 allows up to 160 KB/WG). grid=256 (1
// block/CU), 1024 threads (16 waves), tables staged once, one barrier, then
// a barrier-free grid-stride loop over 256-edge tiles. agg stays bf16.

using bf16 = __hip_bfloat16;
typedef __attribute__((ext_vector_type(8))) short short8;
typedef __attribute__((ext_vector_type(4))) float f32x4;

static __device__ __forceinline__ unsigned short bf16_bits(float x) {
    bf16 h = __float2bfloat16(x);
    unsigned short b;
    __builtin_memcpy(&b, &h, 2);
    return b;
}
static __device__ __forceinline__ unsigned pk2(float x, float y) {
    return (unsigned)bf16_bits(x) | ((unsigned)bf16_bits(y) << 16);
}
static __device__ __forceinline__ float bflo(unsigned u) {
    return __uint_as_float(u << 16);
}
static __device__ __forceinline__ float bfhi(unsigned u) {
    return __uint_as_float(u & 0xffff0000u);
}
union frag_u { short8 s; unsigned u[4]; };

// ------------------------- pack (+ qbias prep) -------------------------
__global__ void k_pack(unsigned short* wkT, unsigned short* wvT, unsigned short* woT,
                       unsigned short* wqhT, unsigned short* wqlT, float* qbias,
                       const float* __restrict__ wk_w, const float* __restrict__ wv_w,
                       const float* __restrict__ wo_w, const float* __restrict__ wq_w,
                       const float* __restrict__ wq_b, const float* __restrict__ time_b) {
    int idx = blockIdx.x * blockDim.x + threadIdx.x;  // 32768
    if (idx < 32768) {
        int n = idx >> 8, k = idx & 255;
        wkT[idx] = bf16_bits(wk_w[(size_t)k * 128 + n]);
        wvT[idx] = bf16_bits(wv_w[(size_t)k * 128 + n]);
        woT[idx] = bf16_bits(wo_w[(size_t)k * 128 + n]);
        if (idx < 16384) {
            int n2 = idx >> 7, k2 = idx & 127;
            float v = wq_w[(size_t)k2 * 128 + n2];
            unsigned short hb = bf16_bits(v);
            wqhT[idx] = hb;
            wqlT[idx] = bf16_bits(v - __uint_as_float((unsigned)hb << 16));
        }
        if (idx < 128) {
            float s = wq_b[idx];
            for (int j = 0; j < 64; ++j)
                s += cosf(time_b[j]) * wq_w[(128 + j) * 128 + idx];
            qbias[idx] = s;
        }
    }
}

// ------------------------- CSR slot assignment -------------------------
__global__ void k_count(const int* __restrict__ edst, int* cnt, int E) {
    int e = blockIdx.x * 256 + threadIdx.x;
    if (e < E) atomicAdd(&cnt[edst[e]], 1);
}

__global__ void k_scan1(const int* __restrict__ cnt, int* rs, int* bsum, int n) {
    __shared__ int s[256];
    int t = threadIdx.x;
    int i = blockIdx.x * 256 + t;
    int v = (i < n) ? cnt[i] : 0;
    s[t] = v;
    __syncthreads();
    for (int off = 1; off < 256; off <<= 1) {
        int x = (t >= off) ? s[t - off] : 0;
        __syncthreads();
        s[t] += x;
        __syncthreads();
    }
    if (i < n) rs[i] = s[t] - v;
    if (t == 255) bsum[blockIdx.x] = s[255];
}

__global__ void k_scan2(int* bsum, int nblk) {
    __shared__ int s[256];
    int t = threadIdx.x;
    int v = (t < nblk) ? bsum[t] : 0;
    s[t] = v;
    __syncthreads();
    for (int off = 1; off < 256; off <<= 1) {
        int x = (t >= off) ? s[t - off] : 0;
        __syncthreads();
        s[t] += x;
        __syncthreads();
    }
    if (t < nblk) bsum[t] = s[t] - v;
}

__global__ void k_scatter(const int* __restrict__ edst, const int* __restrict__ rs,
                          const int* __restrict__ bsum, int* fill, int* epos, int E) {
    int e = blockIdx.x * 256 + threadIdx.x;
    if (e < E) {
        int d = edst[e];
        epos[e] = rs[d] + bsum[d >> 8] + atomicAdd(&fill[d], 1);
    }
}

// ------------------------- Q projection (split-bf16 MFMA, 512 thr) -------------------------
__global__ __launch_bounds__(512) void k_q(
    float* __restrict__ Q, const float* __restrict__ h,
    const unsigned short* __restrict__ wqhT, const unsigned short* __restrict__ wqlT,
    const float* __restrict__ qbias, int ndst)
{
    __shared__ unsigned short Bs[32768];  // Whi [0,16384), Wlo [16384,32768)
    int tid = threadIdx.x;
    int lane = tid & 63, l15 = lane & 15, lk = lane >> 4;
    int r0 = blockIdx.x * 128 + (tid >> 6) * 16;
    int ra = r0 + l15;
    int rc = (ra < ndst) ? ra : (ndst - 1);
    const float* hrow = h + (size_t)rc * 128;

    float4 hx[4][2];
    #pragma unroll
    for (int kk = 0; kk < 4; ++kk) {
        int c0 = kk * 32 + lk * 8;
        hx[kk][0] = *reinterpret_cast<const float4*>(hrow + c0);
        hx[kk][1] = *reinterpret_cast<const float4*>(hrow + c0 + 4);
    }

    #pragma unroll
    for (int it = 0; it < 4; ++it) {
        int i = it * 512 + tid;
        int row = i >> 4, c = i & 15;
        int sw = row * 128 + ((c ^ (row & 15)) << 3);
        *reinterpret_cast<uint4*>(Bs + sw) =
            *reinterpret_cast<const uint4*>(wqhT + (size_t)row * 128 + c * 8);
        *reinterpret_cast<uint4*>(Bs + 16384 + sw) =
            *reinterpret_cast<const uint4*>(wqlT + (size_t)row * 128 + c * 8);
    }

    frag_u ah[4], al[4];
    #pragma unroll
    for (int kk = 0; kk < 4; ++kk) {
        float xs[8] = {hx[kk][0].x, hx[kk][0].y, hx[kk][0].z, hx[kk][0].w,
                       hx[kk][1].x, hx[kk][1].y, hx[kk][1].z, hx[kk][1].w};
        unsigned short hb[8];
        float lo[8];
        #pragma unroll
        for (int t = 0; t < 8; ++t) {
            hb[t] = bf16_bits(xs[t]);
            lo[t] = xs[t] - __uint_as_float((unsigned)hb[t] << 16);
        }
        #pragma unroll
        for (int t = 0; t < 4; ++t)
            ah[kk].u[t] = (unsigned)hb[2*t] | ((unsigned)hb[2*t+1] << 16);
        al[kk].u[0] = pk2(lo[0], lo[1]); al[kk].u[1] = pk2(lo[2], lo[3]);
        al[kk].u[2] = pk2(lo[4], lo[5]); al[kk].u[3] = pk2(lo[6], lo[7]);
    }

    f32x4 ck[8];
    #pragma unroll
    for (int nt = 0; nt < 8; ++nt) ck[nt] = (f32x4){0.f, 0.f, 0.f, 0.f};

    __syncthreads();
    #pragma unroll
    for (int kk2 = 0; kk2 < 4; ++kk2) {
        int co = ((kk2 * 4 + lk) ^ l15) << 3;
        #pragma unroll
        for (int nt = 0; nt < 8; ++nt) {
            int ro = (nt * 16 + l15) * 128;
            short8 bh = *reinterpret_cast<const short8*>(Bs + ro + co);
            short8 bl = *reinterpret_cast<const short8*>(Bs + 16384 + ro + co);
            ck[nt] = __builtin_amdgcn_mfma_f32_16x16x32_bf16(ah[kk2].s, bh, ck[nt], 0, 0, 0);
            ck[nt] = __builtin_amdgcn_mfma_f32_16x16x32_bf16(al[kk2].s, bh, ck[nt], 0, 0, 0);
            ck[nt] = __builtin_amdgcn_mfma_f32_16x16x32_bf16(ah[kk2].s, bl, ck[nt], 0, 0, 0);
        }
    }

    #pragma unroll
    for (int nt = 0; nt < 8; ++nt) {
        int col = nt * 16 + l15;
        float qb = qbias[col];
        #pragma unroll
        for (int j = 0; j < 4; ++j) {
            int row = r0 + lk * 4 + j;
            if (row < ndst) Q[(size_t)row * 128 + col] = ck[nt][j] + qb;
        }
    }
}

// ------------------------- edge pass: persistent, both tables in 128 KB LDS -------------------------
__global__ __launch_bounds__(1024) void k_kvA(
    const float* __restrict__ h, const int* __restrict__ nbr, const int* __restrict__ edst,
    const float* __restrict__ dt, const float* __restrict__ ef,
    const float* __restrict__ time_w, const float* __restrict__ time_b,
    const unsigned short* __restrict__ wkT, const unsigned short* __restrict__ wvT,
    const float* __restrict__ wk_b, const float* __restrict__ Q,
    const int* __restrict__ epos,
    unsigned short* __restrict__ Vbuf, float2* __restrict__ att2,
    int ndst, int E, int ntiles)
{
    __shared__ unsigned short Bs[65536];  // 128 KB: K [0,32768), V [32768,65536)
    int tid  = threadIdx.x;
    int lane = tid & 63;
    int l15  = lane & 15;
    int lk   = lane >> 4;

    // stage both tables once: 2 x 4096 chunks of 16 B, 8 chunks/thread
    #pragma unroll
    for (int it = 0; it < 8; ++it) {
        int i = it * 1024 + tid;              // 0..8191
        int tb  = i >> 12;                     // 0 = K, 1 = V
        int row = (i >> 5) & 127;
        int c   = i & 31;
        const unsigned short* src = tb ? wvT : wkT;
        *reinterpret_cast<uint4*>(Bs + tb * 32768 + row * 256 + ((c ^ (row & 15)) << 3)) =
            *reinterpret_cast<const uint4*>(src + (size_t)row * 256 + c * 8);
    }
    float kb[8];
    #pragma unroll
    for (int nt = 0; nt < 8; ++nt) kb[nt] = wk_b[nt * 16 + l15];
    __syncthreads();

    for (int tile = blockIdx.x; tile < ntiles; tile += gridDim.x) {
        int e0 = tile * 256 + (tid >> 6) * 16;

        int  ea = e0 + l15;
        bool va = ea < E;
        int  na = va ? nbr[ea] : 0;
        float da = va ? dt[ea] : 0.f;
        const float* hrow = h + (size_t)(ndst + na) * 128;
        const float* erow = ef + (size_t)ea * 64;

        int dstr[4], pe[4];
        bool evv[4];
        #pragma unroll
        for (int j = 0; j < 4; ++j) {
            int ed = e0 + lk * 4 + j;
            evv[j]  = ed < E;
            dstr[j] = evv[j] ? edst[ed] : 0;
            pe[j]   = evv[j] ? epos[ed] : 0;
        }

        float4 hx[4][2], ex_[2][2];
        const float4 z4 = make_float4(0.f, 0.f, 0.f, 0.f);
        #pragma unroll
        for (int kk = 0; kk < 4; ++kk) {
            int c0 = kk * 32 + lk * 8;
            hx[kk][0] = va ? *reinterpret_cast<const float4*>(hrow + c0)     : z4;
            hx[kk][1] = va ? *reinterpret_cast<const float4*>(hrow + c0 + 4) : z4;
        }
        #pragma unroll
        for (int t = 0; t < 2; ++t) {
            int c = (4 + t) * 32 + lk * 8 - 128;
            ex_[t][0] = va ? *reinterpret_cast<const float4*>(erow + c)     : z4;
            ex_[t][1] = va ? *reinterpret_cast<const float4*>(erow + c + 4) : z4;
        }

        float qg[8][4];
        #pragma unroll
        for (int nt = 0; nt < 8; ++nt) {
            int gc = nt * 16 + l15;
            #pragma unroll
            for (int j = 0; j < 4; ++j)
                qg[nt][j] = Q[(size_t)dstr[j] * 128 + gc];
        }

        float tf[16];
        {
            int j0 = lk * 8;
            #pragma unroll
            for (int t = 0; t < 8; ++t) tf[t]     = __cosf(fmaf(da, time_w[j0 + t],      time_b[j0 + t]));
            #pragma unroll
            for (int t = 0; t < 8; ++t) tf[8 + t] = __cosf(fmaf(da, time_w[j0 + 32 + t], time_b[j0 + 32 + t]));
        }

        frag_u a[8];
        #pragma unroll
        for (int kk = 0; kk < 4; ++kk) {
            a[kk].u[0] = pk2(hx[kk][0].x, hx[kk][0].y); a[kk].u[1] = pk2(hx[kk][0].z, hx[kk][0].w);
            a[kk].u[2] = pk2(hx[kk][1].x, hx[kk][1].y); a[kk].u[3] = pk2(hx[kk][1].z, hx[kk][1].w);
        }
        #pragma unroll
        for (int t = 0; t < 2; ++t) {
            a[4+t].u[0] = pk2(ex_[t][0].x, ex_[t][0].y); a[4+t].u[1] = pk2(ex_[t][0].z, ex_[t][0].w);
            a[4+t].u[2] = pk2(ex_[t][1].x, ex_[t][1].y); a[4+t].u[3] = pk2(ex_[t][1].z, ex_[t][1].w);
        }
        a[6].u[0] = pk2(tf[0], tf[1]);  a[6].u[1] = pk2(tf[2], tf[3]);
        a[6].u[2] = pk2(tf[4], tf[5]);  a[6].u[3] = pk2(tf[6], tf[7]);
        a[7].u[0] = pk2(tf[8], tf[9]);  a[7].u[1] = pk2(tf[10], tf[11]);
        a[7].u[2] = pk2(tf[12], tf[13]); a[7].u[3] = pk2(tf[14], tf[15]);

        // K GEMM (LDS lower half, no barriers)
        f32x4 ck[8];
        #pragma unroll
        for (int nt = 0; nt < 8; ++nt) ck[nt] = (f32x4){0.f, 0.f, 0.f, 0.f};
        #pragma unroll
        for (int kk2 = 0; kk2 < 8; ++kk2) {
            int co = ((kk2 * 4 + lk) ^ l15) << 3;
            #pragma unroll
            for (int nt = 0; nt < 8; ++nt) {
                short8 b = *reinterpret_cast<const short8*>(Bs + (nt * 16 + l15) * 256 + co);
                ck[nt] = __builtin_amdgcn_mfma_f32_16x16x32_bf16(a[kk2].s, b, ck[nt], 0, 0, 0);
            }
        }

        // att dot + 16-lane reduce, leaky, store
        float p0[4], p1[4];
        #pragma unroll
        for (int j = 0; j < 4; ++j) { p0[j] = 0.f; p1[j] = 0.f; }
        #pragma unroll
        for (int nt = 0; nt < 8; ++nt)
            #pragma unroll
            for (int j = 0; j < 4; ++j) {
                float t = (ck[nt][j] + kb[nt]) * qg[nt][j];
                if (nt < 4) p0[j] += t; else p1[j] += t;
            }
        #pragma unroll
        for (int m = 1; m <= 8; m <<= 1)
            #pragma unroll
            for (int j = 0; j < 4; ++j) {
                p0[j] += __shfl_xor(p0[j], m, 64);
                p1[j] += __shfl_xor(p1[j], m, 64);
            }
        if (l15 == 0) {
            #pragma unroll
            for (int j = 0; j < 4; ++j)
                if (evv[j]) {
                    float r0 = p0[j]; r0 = (r0 >= 0.f) ? r0 : 0.2f * r0;
                    float r1 = p1[j]; r1 = (r1 >= 0.f) ? r1 : 0.2f * r1;
                    att2[pe[j]] = make_float2(r0, r1);
                }
        }

        // V GEMM (LDS upper half, no barriers)
        f32x4 cv[8];
        #pragma unroll
        for (int nt = 0; nt < 8; ++nt) cv[nt] = (f32x4){0.f, 0.f, 0.f, 0.f};
        #pragma unroll
        for (int kk2 = 0; kk2 < 8; ++kk2) {
            int co = ((kk2 * 4 + lk) ^ l15) << 3;
            #pragma unroll
            for (int nt = 0; nt < 8; ++nt) {
                short8 b = *reinterpret_cast<const short8*>(Bs + 32768 + (nt * 16 + l15) * 256 + co);
                cv[nt] = __builtin_amdgcn_mfma_f32_16x16x32_bf16(a[kk2].s, b, cv[nt], 0, 0, 0);
            }
        }

        #pragma unroll
        for (int j = 0; j < 4; ++j)
            if (evv[j]) {
                uint4 val;
                val.x = pk2(cv[0][j], cv[1][j]);
                val.y = pk2(cv[2][j], cv[3][j]);
                val.z = pk2(cv[4][j], cv[5][j]);
                val.w = pk2(cv[6][j], cv[7][j]);
                *reinterpret_cast<uint4*>(Vbuf + (size_t)pe[j] * 128 + l15 * 8) = val;
            }
    }
}

// ------------------------- streaming segment reduction (bf16 out) -------------------------
__global__ __launch_bounds__(256) void k_agg(
    const unsigned short* __restrict__ Vbuf, const float2* __restrict__ att2,
    const int* __restrict__ rs, const int* __restrict__ bsum, const int* __restrict__ cnt,
    const float* __restrict__ wv_b, unsigned short* __restrict__ agg16, int ndst)
{
    int w = threadIdx.x >> 6, lane = threadIdx.x & 63;
    int d = blockIdx.x * 4 + w;
    if (d >= ndst) return;
    int p0 = lane * 2, p1 = p0 + 1;
    int c0 = ((p0 & 7) << 4) + (p0 >> 3);
    int c1 = ((p1 & 7) << 4) + (p1 >> 3);
    bool h0 = (p0 & 4) != 0, h1 = (p1 & 4) != 0;
    int base = rs[d] + bsum[d >> 8], n = cnt[d];
    const unsigned* V32 = reinterpret_cast<const unsigned*>(Vbuf);
    float den0 = 0.f, den1 = 0.f, acc0 = 0.f, acc1 = 0.f;
    int i = 0;
    for (; i + 4 <= n; i += 4) {
        size_t r = (size_t)(base + i);
        float2 a0 = att2[r], a1 = att2[r+1], a2 = att2[r+2], a3 = att2[r+3];
        unsigned w0 = V32[r*64 + lane], w1 = V32[(r+1)*64 + lane];
        unsigned w2 = V32[(r+2)*64 + lane], w3 = V32[(r+3)*64 + lane];
        float e00 = __expf(a0.x), e01 = __expf(a0.y);
        float e10 = __expf(a1.x), e11 = __expf(a1.y);
        float e20 = __expf(a2.x), e21 = __expf(a2.y);
        float e30 = __expf(a3.x), e31 = __expf(a3.y);
        den0 += e00 + e10 + e20 + e30;
        den1 += e01 + e11 + e21 + e31;
        acc0 = fmaf(h0 ? e01 : e00, bflo(w0), acc0);
        acc1 = fmaf(h1 ? e01 : e00, bfhi(w0), acc1);
        acc0 = fmaf(h0 ? e11 : e10, bflo(w1), acc0);
        acc1 = fmaf(h1 ? e11 : e10, bfhi(w1), acc1);
        acc0 = fmaf(h0 ? e21 : e20, bflo(w2), acc0);
        acc1 = fmaf(h1 ? e21 : e20, bfhi(w2), acc1);
        acc0 = fmaf(h0 ? e31 : e30, bflo(w3), acc0);
        acc1 = fmaf(h1 ? e31 : e30, bfhi(w3), acc1);
    }
    for (; i < n; ++i) {
        size_t r = (size_t)(base + i);
        float2 at = att2[r];
        float ex0 = __expf(at.x), ex1 = __expf(at.y);
        den0 += ex0; den1 += ex1;
        unsigned vv = V32[r*64 + lane];
        acc0 = fmaf(h0 ? ex1 : ex0, bflo(vv), acc0);
        acc1 = fmaf(h1 ? ex1 : ex0, bfhi(vv), acc1);
    }
    float o0 = 0.f, o1 = 0.f;
    if (n > 0) {
        o0 = acc0 / (h0 ? den1 : den0) + wv_b[c0];
        o1 = acc1 / (h1 ? den1 : den0) + wv_b[c1];
    }
    agg16[(size_t)d * 128 + c0] = bf16_bits(o0);
    agg16[(size_t)d * 128 + c1] = bf16_bits(o1);
}

// ------------------------- output (bf16 MFMA + ReLU + LayerNorm, 512 thr) -------------------------
__global__ __launch_bounds__(512) void k_out(
    const unsigned short* __restrict__ agg16, const float* __restrict__ h,
    const unsigned short* __restrict__ woT, const float* __restrict__ wo_b,
    const float* __restrict__ ln_g, const float* __restrict__ ln_b,
    float* __restrict__ out, int ndst)
{
    __shared__ unsigned short Bs[32768];  // 64 KB full woT
    int tid = threadIdx.x;
    int lane = tid & 63, l15 = lane & 15, lk = lane >> 4;
    int r0 = blockIdx.x * 128 + (tid >> 6) * 16;
    int ra = r0 + l15;
    int rc = (ra < ndst) ? ra : (ndst - 1);
    const unsigned short* arow = agg16 + (size_t)rc * 128;
    const float* hrow = h + (size_t)rc * 128;

    frag_u aa[4];
    float4 hx[4][2];
    #pragma unroll
    for (int kk = 0; kk < 4; ++kk) {
        int c0 = kk * 32 + lk * 8;
        aa[kk].s = *reinterpret_cast<const short8*>(arow + c0);
        hx[kk][0] = *reinterpret_cast<const float4*>(hrow + c0);
        hx[kk][1] = *reinterpret_cast<const float4*>(hrow + c0 + 4);
    }

    #pragma unroll
    for (int it = 0; it < 8; ++it) {
        int i = it * 512 + tid;
        int row = i >> 5, c = i & 31;
        uint4 v = *reinterpret_cast<const uint4*>(woT + (size_t)row * 256 + c * 8);
        *reinterpret_cast<uint4*>(Bs + row * 256 + ((c ^ (row & 15)) << 3)) = v;
    }

    frag_u ah[4];
    #pragma unroll
    for (int kk = 0; kk < 4; ++kk) {
        ah[kk].u[0] = pk2(hx[kk][0].x, hx[kk][0].y); ah[kk].u[1] = pk2(hx[kk][0].z, hx[kk][0].w);
        ah[kk].u[2] = pk2(hx[kk][1].x, hx[kk][1].y); ah[kk].u[3] = pk2(hx[kk][1].z, hx[kk][1].w);
    }

    f32x4 ck[8];
    #pragma unroll
    for (int nt = 0; nt < 8; ++nt) ck[nt] = (f32x4){0.f, 0.f, 0.f, 0.f};

    __syncthreads();
    #pragma unroll
    for (int kk2 = 0; kk2 < 4; ++kk2) {
        int coA = ((kk2 * 4 + lk) ^ l15) << 3;          // chunks 0..15 (agg half)
        int coH = (((16 + kk2 * 4 + lk)) ^ l15) << 3;   // chunks 16..31 (h half)
        #pragma unroll
        for (int nt = 0; nt < 8; ++nt) {
            int ro = (nt * 16 + l15) * 256;
            short8 bA = *reinterpret_cast<const short8*>(Bs + ro + coA);
            short8 bH = *reinterpret_cast<const short8*>(Bs + ro + coH);
            ck[nt] = __builtin_amdgcn_mfma_f32_16x16x32_bf16(aa[kk2].s, bA, ck[nt], 0, 0, 0);
            ck[nt] = __builtin_amdgcn_mfma_f32_16x16x32_bf16(ah[kk2].s, bH, ck[nt], 0, 0, 0);
        }
    }

    #pragma unroll
    for (int nt = 0; nt < 8; ++nt) {
        float bo = wo_b[nt * 16 + l15];
        #pragma unroll
        for (int j = 0; j < 4; ++j)
            ck[nt][j] = fmaxf(ck[nt][j] + bo, 0.f);
    }
    float s1[4], s2[4];
    #pragma unroll
    for (int j = 0; j < 4; ++j) { s1[j] = 0.f; s2[j] = 0.f; }
    #pragma unroll
    for (int nt = 0; nt < 8; ++nt)
        #pragma unroll
        for (int j = 0; j < 4; ++j) {
            s1[j] += ck[nt][j];
            s2[j] = fmaf(ck[nt][j], ck[nt][j], s2[j]);
        }
    #pragma unroll
    for (int m = 1; m <= 8; m <<= 1)
        #pragma unroll
        for (int j = 0; j < 4; ++j) {
            s1[j] += __shfl_xor(s1[j], m, 64);
            s2[j] += __shfl_xor(s2[j], m, 64);
        }
    float mean[4], rstd[4];
    #pragma unroll
    for (int j = 0; j < 4; ++j) {
        mean[j] = s1[j] * (1.f / 128.f);
        float var = s2[j] * (1.f / 128.f) - mean[j] * mean[j];
        rstd[j] = rsqrtf(var + 1e-5f);
    }
    #pragma unroll
    for (int nt = 0; nt < 8; ++nt) {
        int col = nt * 16 + l15;
        float g = ln_g[col], lb = ln_b[col];
        #pragma unroll
        for (int j = 0; j < 4; ++j) {
            int row = r0 + lk * 4 + j;
            if (row < ndst)
                out[(size_t)row * 128 + col] = (ck[nt][j] - mean[j]) * rstd[j] * g + lb;
        }
    }
}

extern "C" void kernel_launch(void* const* d_in, const int* in_sizes, int n_in,
                              void* d_out, int out_size, void* d_ws, size_t ws_size,
                              hipStream_t stream) {
    const float* h      = (const float*)d_in[0];
    const float* dt     = (const float*)d_in[1];
    const float* ef     = (const float*)d_in[2];
    const float* time_w = (const float*)d_in[3];
    const float* time_b = (const float*)d_in[4];
    const float* wq_w   = (const float*)d_in[5];
    const float* wq_b   = (const float*)d_in[6];
    const float* wk_w   = (const float*)d_in[7];
    const float* wk_b   = (const float*)d_in[8];
    const float* wv_w   = (const float*)d_in[9];
    const float* wv_b   = (const float*)d_in[10];
    const float* wo_w   = (const float*)d_in[11];
    const float* wo_b   = (const float*)d_in[12];
    const float* ln_g   = (const float*)d_in[13];
    const float* ln_b   = (const float*)d_in[14];
    const int* nbr      = (const int*)d_in[15];
    const int* edst     = (const int*)d_in[16];

    int E    = in_sizes[1];
    int ndst = out_size / 128;
    int nblk = (ndst + 255) / 256;
    int ntiles = (E + 255) / 256;

    char* wsb = (char*)d_ws;
    float* qbias = (float*)wsb;                 wsb += 512;
    float* Q     = (float*)wsb;                 wsb += (size_t)ndst * 128 * 4;
    unsigned short* agg16 = (unsigned short*)wsb; wsb += (size_t)ndst * 128 * 2;
    unsigned short* wkT  = (unsigned short*)wsb; wsb += 32768 * 2;
    unsigned short* wvT  = (unsigned short*)wsb; wsb += 32768 * 2;
    unsigned short* woT  = (unsigned short*)wsb; wsb += 32768 * 2;
    unsigned short* wqhT = (unsigned short*)wsb; wsb += 16384 * 2;
    unsigned short* wqlT = (unsigned short*)wsb; wsb += 16384 * 2;
    int* cnt    = (int*)wsb;                    wsb += (size_t)ndst * 4;
    int* fill   = (int*)wsb;                    wsb += (size_t)ndst * 4;
    int* rs     = (int*)wsb;                    wsb += (size_t)ndst * 4;
    int* bsum   = (int*)wsb;                    wsb += 1024;
    int* epos   = (int*)wsb;                    wsb += (size_t)E * 4;
    float2* att2 = (float2*)wsb;                wsb += (size_t)E * 8;
    unsigned short* Vbuf = (unsigned short*)wsb; wsb += (size_t)E * 128 * 2;

    hipMemsetAsync(cnt, 0, (size_t)ndst * 8, stream);  // cnt + fill (adjacent)
    k_pack<<<128, 256, 0, stream>>>(wkT, wvT, woT, wqhT, wqlT, qbias,
                                    wk_w, wv_w, wo_w, wq_w, wq_b, time_b);
    k_count<<<(E + 255) / 256, 256, 0, stream>>>(edst, cnt, E);
    k_scan1<<<nblk, 256, 0, stream>>>(cnt, rs, bsum, ndst);
    k_scan2<<<1, 256, 0, stream>>>(bsum, nblk);
    k_scatter<<<(E + 255) / 256, 256, 0, stream>>>(edst, rs, bsum, fill, epos, E);
    k_q<<<(ndst + 127) / 128, 512, 0, stream>>>(Q, h, wqhT, wqlT, qbias, ndst);
    k_kvA<<<256, 1024, 0, stream>>>(h, nbr, edst, dt, ef, time_w, time_b,
                                    wkT, wvT, wk_b, Q, epos, Vbuf, att2,
                                    ndst, E, ntiles);
    k_agg<<<(ndst + 3) / 4, 256, 0, stream>>>(Vbuf, att2, rs, bsum, cnt, wv_b, agg16, ndst);
    k_out<<<(ndst + 127) / 128, 512, 0, stream>>>(agg16, h, woT, wo_b, ln_g, ln_b,
                                                  (float*)d_out, ndst);
}

// Round 14
// 662.796 us; speedup vs baseline: 1.2736x; 1.2736x over previous
//
#include <hip/hip_runtime.h>
#include <hip/hip_bf16.h>
#include <math.h>

// TemporalTransformerConv (TGAT-like) for MI355X — round 14.
// Round 13's persistent edge kernel with 512-thread blocks (8 waves): VGPR
// budget 256/wave -> no spills (r13's 1024-thr block clamped VGPR to 64 and
// spilled: 1.9 GB traffic). 128 KB LDS holds both B tables; staged once;
// one barrier; barrier-free grid-stride loop over 128-edge tiles.

using bf16 = __hip_bfloat16;
typedef __attribute__((ext_vector_type(8))) short short8;
typedef __attribute__((ext_vector_type(4))) float f32x4;

static __device__ __forceinline__ unsigned short bf16_bits(float x) {
    bf16 h = __float2bfloat16(x);
    unsigned short b;
    __builtin_memcpy(&b, &h, 2);
    return b;
}
static __device__ __forceinline__ unsigned pk2(float x, float y) {
    return (unsigned)bf16_bits(x) | ((unsigned)bf16_bits(y) << 16);
}
static __device__ __forceinline__ float bflo(unsigned u) {
    return __uint_as_float(u << 16);
}
static __device__ __forceinline__ float bfhi(unsigned u) {
    return __uint_as_float(u & 0xffff0000u);
}
union frag_u { short8 s; unsigned u[4]; };

// ------------------------- pack (+ qbias prep) -------------------------
__global__ void k_pack(unsigned short* wkT, unsigned short* wvT, unsigned short* woT,
                       unsigned short* wqhT, unsigned short* wqlT, float* qbias,
                       const float* __restrict__ wk_w, const float* __restrict__ wv_w,
                       const float* __restrict__ wo_w, const float* __restrict__ wq_w,
                       const float* __restrict__ wq_b, const float* __restrict__ time_b) {
    int idx = blockIdx.x * blockDim.x + threadIdx.x;  // 32768
    if (idx < 32768) {
        int n = idx >> 8, k = idx & 255;
        wkT[idx] = bf16_bits(wk_w[(size_t)k * 128 + n]);
        wvT[idx] = bf16_bits(wv_w[(size_t)k * 128 + n]);
        woT[idx] = bf16_bits(wo_w[(size_t)k * 128 + n]);
        if (idx < 16384) {
            int n2 = idx >> 7, k2 = idx & 127;
            float v = wq_w[(size_t)k2 * 128 + n2];
            unsigned short hb = bf16_bits(v);
            wqhT[idx] = hb;
            wqlT[idx] = bf16_bits(v - __uint_as_float((unsigned)hb << 16));
        }
        if (idx < 128) {
            float s = wq_b[idx];
            for (int j = 0; j < 64; ++j)
                s += cosf(time_b[j]) * wq_w[(128 + j) * 128 + idx];
            qbias[idx] = s;
        }
    }
}

// ------------------------- CSR slot assignment -------------------------
__global__ void k_count(const int* __restrict__ edst, int* cnt, int E) {
    int e = blockIdx.x * 256 + threadIdx.x;
    if (e < E) atomicAdd(&cnt[edst[e]], 1);
}

__global__ void k_scan1(const int* __restrict__ cnt, int* rs, int* bsum, int n) {
    __shared__ int s[256];
    int t = threadIdx.x;
    int i = blockIdx.x * 256 + t;
    int v = (i < n) ? cnt[i] : 0;
    s[t] = v;
    __syncthreads();
    for (int off = 1; off < 256; off <<= 1) {
        int x = (t >= off) ? s[t - off] : 0;
        __syncthreads();
        s[t] += x;
        __syncthreads();
    }
    if (i < n) rs[i] = s[t] - v;
    if (t == 255) bsum[blockIdx.x] = s[255];
}

__global__ void k_scan2(int* bsum, int nblk) {
    __shared__ int s[256];
    int t = threadIdx.x;
    int v = (t < nblk) ? bsum[t] : 0;
    s[t] = v;
    __syncthreads();
    for (int off = 1; off < 256; off <<= 1) {
        int x = (t >= off) ? s[t - off] : 0;
        __syncthreads();
        s[t] += x;
        __syncthreads();
    }
    if (t < nblk) bsum[t] = s[t] - v;
}

__global__ void k_scatter(const int* __restrict__ edst, const int* __restrict__ rs,
                          const int* __restrict__ bsum, int* fill, int* epos, int E) {
    int e = blockIdx.x * 256 + threadIdx.x;
    if (e < E) {
        int d = edst[e];
        epos[e] = rs[d] + bsum[d >> 8] + atomicAdd(&fill[d], 1);
    }
}

// ------------------------- Q projection (split-bf16 MFMA, 512 thr) -------------------------
__global__ __launch_bounds__(512) void k_q(
    float* __restrict__ Q, const float* __restrict__ h,
    const unsigned short* __restrict__ wqhT, const unsigned short* __restrict__ wqlT,
    const float* __restrict__ qbias, int ndst)
{
    __shared__ unsigned short Bs[32768];  // Whi [0,16384), Wlo [16384,32768)
    int tid = threadIdx.x;
    int lane = tid & 63, l15 = lane & 15, lk = lane >> 4;
    int r0 = blockIdx.x * 128 + (tid >> 6) * 16;
    int ra = r0 + l15;
    int rc = (ra < ndst) ? ra : (ndst - 1);
    const float* hrow = h + (size_t)rc * 128;

    float4 hx[4][2];
    #pragma unroll
    for (int kk = 0; kk < 4; ++kk) {
        int c0 = kk * 32 + lk * 8;
        hx[kk][0] = *reinterpret_cast<const float4*>(hrow + c0);
        hx[kk][1] = *reinterpret_cast<const float4*>(hrow + c0 + 4);
    }

    #pragma unroll
    for (int it = 0; it < 4; ++it) {
        int i = it * 512 + tid;
        int row = i >> 4, c = i & 15;
        int sw = row * 128 + ((c ^ (row & 15)) << 3);
        *reinterpret_cast<uint4*>(Bs + sw) =
            *reinterpret_cast<const uint4*>(wqhT + (size_t)row * 128 + c * 8);
        *reinterpret_cast<uint4*>(Bs + 16384 + sw) =
            *reinterpret_cast<const uint4*>(wqlT + (size_t)row * 128 + c * 8);
    }

    frag_u ah[4], al[4];
    #pragma unroll
    for (int kk = 0; kk < 4; ++kk) {
        float xs[8] = {hx[kk][0].x, hx[kk][0].y, hx[kk][0].z, hx[kk][0].w,
                       hx[kk][1].x, hx[kk][1].y, hx[kk][1].z, hx[kk][1].w};
        unsigned short hb[8];
        float lo[8];
        #pragma unroll
        for (int t = 0; t < 8; ++t) {
            hb[t] = bf16_bits(xs[t]);
            lo[t] = xs[t] - __uint_as_float((unsigned)hb[t] << 16);
        }
        #pragma unroll
        for (int t = 0; t < 4; ++t)
            ah[kk].u[t] = (unsigned)hb[2*t] | ((unsigned)hb[2*t+1] << 16);
        al[kk].u[0] = pk2(lo[0], lo[1]); al[kk].u[1] = pk2(lo[2], lo[3]);
        al[kk].u[2] = pk2(lo[4], lo[5]); al[kk].u[3] = pk2(lo[6], lo[7]);
    }

    f32x4 ck[8];
    #pragma unroll
    for (int nt = 0; nt < 8; ++nt) ck[nt] = (f32x4){0.f, 0.f, 0.f, 0.f};

    __syncthreads();
    #pragma unroll
    for (int kk2 = 0; kk2 < 4; ++kk2) {
        int co = ((kk2 * 4 + lk) ^ l15) << 3;
        #pragma unroll
        for (int nt = 0; nt < 8; ++nt) {
            int ro = (nt * 16 + l15) * 128;
            short8 bh = *reinterpret_cast<const short8*>(Bs + ro + co);
            short8 bl = *reinterpret_cast<const short8*>(Bs + 16384 + ro + co);
            ck[nt] = __builtin_amdgcn_mfma_f32_16x16x32_bf16(ah[kk2].s, bh, ck[nt], 0, 0, 0);
            ck[nt] = __builtin_amdgcn_mfma_f32_16x16x32_bf16(al[kk2].s, bh, ck[nt], 0, 0, 0);
            ck[nt] = __builtin_amdgcn_mfma_f32_16x16x32_bf16(ah[kk2].s, bl, ck[nt], 0, 0, 0);
        }
    }

    #pragma unroll
    for (int nt = 0; nt < 8; ++nt) {
        int col = nt * 16 + l15;
        float qb = qbias[col];
        #pragma unroll
        for (int j = 0; j < 4; ++j) {
            int row = r0 + lk * 4 + j;
            if (row < ndst) Q[(size_t)row * 128 + col] = ck[nt][j] + qb;
        }
    }
}

// ------------------------- edge pass: persistent, both tables in 128 KB LDS, 8 waves -------------------------
__global__ __launch_bounds__(512) void k_kvA(
    const float* __restrict__ h, const int* __restrict__ nbr, const int* __restrict__ edst,
    const float* __restrict__ dt, const float* __restrict__ ef,
    const float* __restrict__ time_w, const float* __restrict__ time_b,
    const unsigned short* __restrict__ wkT, const unsigned short* __restrict__ wvT,
    const float* __restrict__ wk_b, const float* __restrict__ Q,
    const int* __restrict__ epos,
    unsigned short* __restrict__ Vbuf, float2* __restrict__ att2,
    int ndst, int E, int ntiles)
{
    __shared__ unsigned short Bs[65536];  // 128 KB: K [0,32768), V [32768,65536)
    int tid  = threadIdx.x;
    int lane = tid & 63;
    int l15  = lane & 15;
    int lk   = lane >> 4;

    // stage both tables once: 8192 chunks of 16 B, 16/thread
    #pragma unroll
    for (int it = 0; it < 16; ++it) {
        int i = it * 512 + tid;               // 0..8191
        int tb  = i >> 12;                    // 0 = K, 1 = V
        int row = (i >> 5) & 127;
        int c   = i & 31;
        const unsigned short* src = tb ? wvT : wkT;
        *reinterpret_cast<uint4*>(Bs + tb * 32768 + row * 256 + ((c ^ (row & 15)) << 3)) =
            *reinterpret_cast<const uint4*>(src + (size_t)row * 256 + c * 8);
    }
    float kb[8];
    #pragma unroll
    for (int nt = 0; nt < 8; ++nt) kb[nt] = wk_b[nt * 16 + l15];
    __syncthreads();

    for (int tile = blockIdx.x; tile < ntiles; tile += gridDim.x) {
        int e0 = tile * 128 + (tid >> 6) * 16;

        int  ea = e0 + l15;
        bool va = ea < E;
        int  na = va ? nbr[ea] : 0;
        float da = va ? dt[ea] : 0.f;
        const float* hrow = h + (size_t)(ndst + na) * 128;
        const float* erow = ef + (size_t)ea * 64;

        int dstr[4], pe[4];
        bool evv[4];
        #pragma unroll
        for (int j = 0; j < 4; ++j) {
            int ed = e0 + lk * 4 + j;
            evv[j]  = ed < E;
            dstr[j] = evv[j] ? edst[ed] : 0;
            pe[j]   = evv[j] ? epos[ed] : 0;
        }

        float4 hx[4][2], ex_[2][2];
        const float4 z4 = make_float4(0.f, 0.f, 0.f, 0.f);
        #pragma unroll
        for (int kk = 0; kk < 4; ++kk) {
            int c0 = kk * 32 + lk * 8;
            hx[kk][0] = va ? *reinterpret_cast<const float4*>(hrow + c0)     : z4;
            hx[kk][1] = va ? *reinterpret_cast<const float4*>(hrow + c0 + 4) : z4;
        }
        #pragma unroll
        for (int t = 0; t < 2; ++t) {
            int c = (4 + t) * 32 + lk * 8 - 128;
            ex_[t][0] = va ? *reinterpret_cast<const float4*>(erow + c)     : z4;
            ex_[t][1] = va ? *reinterpret_cast<const float4*>(erow + c + 4) : z4;
        }

        float qg[8][4];
        #pragma unroll
        for (int nt = 0; nt < 8; ++nt) {
            int gc = nt * 16 + l15;
            #pragma unroll
            for (int j = 0; j < 4; ++j)
                qg[nt][j] = Q[(size_t)dstr[j] * 128 + gc];
        }

        float tf[16];
        {
            int j0 = lk * 8;
            #pragma unroll
            for (int t = 0; t < 8; ++t) tf[t]     = __cosf(fmaf(da, time_w[j0 + t],      time_b[j0 + t]));
            #pragma unroll
            for (int t = 0; t < 8; ++t) tf[8 + t] = __cosf(fmaf(da, time_w[j0 + 32 + t], time_b[j0 + 32 + t]));
        }

        frag_u a[8];
        #pragma unroll
        for (int kk = 0; kk < 4; ++kk) {
            a[kk].u[0] = pk2(hx[kk][0].x, hx[kk][0].y); a[kk].u[1] = pk2(hx[kk][0].z, hx[kk][0].w);
            a[kk].u[2] = pk2(hx[kk][1].x, hx[kk][1].y); a[kk].u[3] = pk2(hx[kk][1].z, hx[kk][1].w);
        }
        #pragma unroll
        for (int t = 0; t < 2; ++t) {
            a[4+t].u[0] = pk2(ex_[t][0].x, ex_[t][0].y); a[4+t].u[1] = pk2(ex_[t][0].z, ex_[t][0].w);
            a[4+t].u[2] = pk2(ex_[t][1].x, ex_[t][1].y); a[4+t].u[3] = pk2(ex_[t][1].z, ex_[t][1].w);
        }
        a[6].u[0] = pk2(tf[0], tf[1]);  a[6].u[1] = pk2(tf[2], tf[3]);
        a[6].u[2] = pk2(tf[4], tf[5]);  a[6].u[3] = pk2(tf[6], tf[7]);
        a[7].u[0] = pk2(tf[8], tf[9]);  a[7].u[1] = pk2(tf[10], tf[11]);
        a[7].u[2] = pk2(tf[12], tf[13]); a[7].u[3] = pk2(tf[14], tf[15]);

        // K GEMM (LDS lower half, no barriers)
        f32x4 ck[8];
        #pragma unroll
        for (int nt = 0; nt < 8; ++nt) ck[nt] = (f32x4){0.f, 0.f, 0.f, 0.f};
        #pragma unroll
        for (int kk2 = 0; kk2 < 8; ++kk2) {
            int co = ((kk2 * 4 + lk) ^ l15) << 3;
            #pragma unroll
            for (int nt = 0; nt < 8; ++nt) {
                short8 b = *reinterpret_cast<const short8*>(Bs + (nt * 16 + l15) * 256 + co);
                ck[nt] = __builtin_amdgcn_mfma_f32_16x16x32_bf16(a[kk2].s, b, ck[nt], 0, 0, 0);
            }
        }

        // att dot + 16-lane reduce, leaky, store
        float p0[4], p1[4];
        #pragma unroll
        for (int j = 0; j < 4; ++j) { p0[j] = 0.f; p1[j] = 0.f; }
        #pragma unroll
        for (int nt = 0; nt < 8; ++nt)
            #pragma unroll
            for (int j = 0; j < 4; ++j) {
                float t = (ck[nt][j] + kb[nt]) * qg[nt][j];
                if (nt < 4) p0[j] += t; else p1[j] += t;
            }
        #pragma unroll
        for (int m = 1; m <= 8; m <<= 1)
            #pragma unroll
            for (int j = 0; j < 4; ++j) {
                p0[j] += __shfl_xor(p0[j], m, 64);
                p1[j] += __shfl_xor(p1[j], m, 64);
            }
        if (l15 == 0) {
            #pragma unroll
            for (int j = 0; j < 4; ++j)
                if (evv[j]) {
                    float r0 = p0[j]; r0 = (r0 >= 0.f) ? r0 : 0.2f * r0;
                    float r1 = p1[j]; r1 = (r1 >= 0.f) ? r1 : 0.2f * r1;
                    att2[pe[j]] = make_float2(r0, r1);
                }
        }

        // V GEMM (LDS upper half, no barriers)
        f32x4 cv[8];
        #pragma unroll
        for (int nt = 0; nt < 8; ++nt) cv[nt] = (f32x4){0.f, 0.f, 0.f, 0.f};
        #pragma unroll
        for (int kk2 = 0; kk2 < 8; ++kk2) {
            int co = ((kk2 * 4 + lk) ^ l15) << 3;
            #pragma unroll
            for (int nt = 0; nt < 8; ++nt) {
                short8 b = *reinterpret_cast<const short8*>(Bs + 32768 + (nt * 16 + l15) * 256 + co);
                cv[nt] = __builtin_amdgcn_mfma_f32_16x16x32_bf16(a[kk2].s, b, cv[nt], 0, 0, 0);
            }
        }

        #pragma unroll
        for (int j = 0; j < 4; ++j)
            if (evv[j]) {
                uint4 val;
                val.x = pk2(cv[0][j], cv[1][j]);
                val.y = pk2(cv[2][j], cv[3][j]);
                val.z = pk2(cv[4][j], cv[5][j]);
                val.w = pk2(cv[6][j], cv[7][j]);
                *reinterpret_cast<uint4*>(Vbuf + (size_t)pe[j] * 128 + l15 * 8) = val;
            }
    }
}

// ------------------------- streaming segment reduction (bf16 out) -------------------------
__global__ __launch_bounds__(256) void k_agg(
    const unsigned short* __restrict__ Vbuf, const float2* __restrict__ att2,
    const int* __restrict__ rs, const int* __restrict__ bsum, const int* __restrict__ cnt,
    const float* __restrict__ wv_b, unsigned short* __restrict__ agg16, int ndst)
{
    int w = threadIdx.x >> 6, lane = threadIdx.x & 63;
    int d = blockIdx.x * 4 + w;
    if (d >= ndst) return;
    int p0 = lane * 2, p1 = p0 + 1;
    int c0 = ((p0 & 7) << 4) + (p0 >> 3);
    int c1 = ((p1 & 7) << 4) + (p1 >> 3);
    bool h0 = (p0 & 4) != 0, h1 = (p1 & 4) != 0;
    int base = rs[d] + bsum[d >> 8], n = cnt[d];
    const unsigned* V32 = reinterpret_cast<const unsigned*>(Vbuf);
    float den0 = 0.f, den1 = 0.f, acc0 = 0.f, acc1 = 0.f;
    int i = 0;
    for (; i + 4 <= n; i += 4) {
        size_t r = (size_t)(base + i);
        float2 a0 = att2[r], a1 = att2[r+1], a2 = att2[r+2], a3 = att2[r+3];
        unsigned w0 = V32[r*64 + lane], w1 = V32[(r+1)*64 + lane];
        unsigned w2 = V32[(r+2)*64 + lane], w3 = V32[(r+3)*64 + lane];
        float e00 = __expf(a0.x), e01 = __expf(a0.y);
        float e10 = __expf(a1.x), e11 = __expf(a1.y);
        float e20 = __expf(a2.x), e21 = __expf(a2.y);
        float e30 = __expf(a3.x), e31 = __expf(a3.y);
        den0 += e00 + e10 + e20 + e30;
        den1 += e01 + e11 + e21 + e31;
        acc0 = fmaf(h0 ? e01 : e00, bflo(w0), acc0);
        acc1 = fmaf(h1 ? e01 : e00, bfhi(w0), acc1);
        acc0 = fmaf(h0 ? e11 : e10, bflo(w1), acc0);
        acc1 = fmaf(h1 ? e11 : e10, bfhi(w1), acc1);
        acc0 = fmaf(h0 ? e21 : e20, bflo(w2), acc0);
        acc1 = fmaf(h1 ? e21 : e20, bfhi(w2), acc1);
        acc0 = fmaf(h0 ? e31 : e30, bflo(w3), acc0);
        acc1 = fmaf(h1 ? e31 : e30, bfhi(w3), acc1);
    }
    for (; i < n; ++i) {
        size_t r = (size_t)(base + i);
        float2 at = att2[r];
        float ex0 = __expf(at.x), ex1 = __expf(at.y);
        den0 += ex0; den1 += ex1;
        unsigned vv = V32[r*64 + lane];
        acc0 = fmaf(h0 ? ex1 : ex0, bflo(vv), acc0);
        acc1 = fmaf(h1 ? ex1 : ex0, bfhi(vv), acc1);
    }
    float o0 = 0.f, o1 = 0.f;
    if (n > 0) {
        o0 = acc0 / (h0 ? den1 : den0) + wv_b[c0];
        o1 = acc1 / (h1 ? den1 : den0) + wv_b[c1];
    }
    agg16[(size_t)d * 128 + c0] = bf16_bits(o0);
    agg16[(size_t)d * 128 + c1] = bf16_bits(o1);
}

// ------------------------- output (bf16 MFMA + ReLU + LayerNorm, 512 thr) -------------------------
__global__ __launch_bounds__(512) void k_out(
    const unsigned short* __restrict__ agg16, const float* __restrict__ h,
    const unsigned short* __restrict__ woT, const float* __restrict__ wo_b,
    const float* __restrict__ ln_g, const float* __restrict__ ln_b,
    float* __restrict__ out, int ndst)
{
    __shared__ unsigned short Bs[32768];  // 64 KB full woT
    int tid = threadIdx.x;
    int lane = tid & 63, l15 = lane & 15, lk = lane >> 4;
    int r0 = blockIdx.x * 128 + (tid >> 6) * 16;
    int ra = r0 + l15;
    int rc = (ra < ndst) ? ra : (ndst - 1);
    const unsigned short* arow = agg16 + (size_t)rc * 128;
    const float* hrow = h + (size_t)rc * 128;

    frag_u aa[4];
    float4 hx[4][2];
    #pragma unroll
    for (int kk = 0; kk < 4; ++kk) {
        int c0 = kk * 32 + lk * 8;
        aa[kk].s = *reinterpret_cast<const short8*>(arow + c0);
        hx[kk][0] = *reinterpret_cast<const float4*>(hrow + c0);
        hx[kk][1] = *reinterpret_cast<const float4*>(hrow + c0 + 4);
    }

    #pragma unroll
    for (int it = 0; it < 8; ++it) {
        int i = it * 512 + tid;
        int row = i >> 5, c = i & 31;
        uint4 v = *reinterpret_cast<const uint4*>(woT + (size_t)row * 256 + c * 8);
        *reinterpret_cast<uint4*>(Bs + row * 256 + ((c ^ (row & 15)) << 3)) = v;
    }

    frag_u ah[4];
    #pragma unroll
    for (int kk = 0; kk < 4; ++kk) {
        ah[kk].u[0] = pk2(hx[kk][0].x, hx[kk][0].y); ah[kk].u[1] = pk2(hx[kk][0].z, hx[kk][0].w);
        ah[kk].u[2] = pk2(hx[kk][1].x, hx[kk][1].y); ah[kk].u[3] = pk2(hx[kk][1].z, hx[kk][1].w);
    }

    f32x4 ck[8];
    #pragma unroll
    for (int nt = 0; nt < 8; ++nt) ck[nt] = (f32x4){0.f, 0.f, 0.f, 0.f};

    __syncthreads();
    #pragma unroll
    for (int kk2 = 0; kk2 < 4; ++kk2) {
        int coA = ((kk2 * 4 + lk) ^ l15) << 3;          // chunks 0..15 (agg half)
        int coH = (((16 + kk2 * 4 + lk)) ^ l15) << 3;   // chunks 16..31 (h half)
        #pragma unroll
        for (int nt = 0; nt < 8; ++nt) {
            int ro = (nt * 16 + l15) * 256;
            short8 bA = *reinterpret_cast<const short8*>(Bs + ro + coA);
            short8 bH = *reinterpret_cast<const short8*>(Bs + ro + coH);
            ck[nt] = __builtin_amdgcn_mfma_f32_16x16x32_bf16(aa[kk2].s, bA, ck[nt], 0, 0, 0);
            ck[nt] = __builtin_amdgcn_mfma_f32_16x16x32_bf16(ah[kk2].s, bH, ck[nt], 0, 0, 0);
        }
    }

    #pragma unroll
    for (int nt = 0; nt < 8; ++nt) {
        float bo = wo_b[nt * 16 + l15];
        #pragma unroll
        for (int j = 0; j < 4; ++j)
            ck[nt][j] = fmaxf(ck[nt][j] + bo, 0.f);
    }
    float s1[4], s2[4];
    #pragma unroll
    for (int j = 0; j < 4; ++j) { s1[j] = 0.f; s2[j] = 0.f; }
    #pragma unroll
    for (int nt = 0; nt < 8; ++nt)
        #pragma unroll
        for (int j = 0; j < 4; ++j) {
            s1[j] += ck[nt][j];
            s2[j] = fmaf(ck[nt][j], ck[nt][j], s2[j]);
        }
    #pragma unroll
    for (int m = 1; m <= 8; m <<= 1)
        #pragma unroll
        for (int j = 0; j < 4; ++j) {
            s1[j] += __shfl_xor(s1[j], m, 64);
            s2[j] += __shfl_xor(s2[j], m, 64);
        }
    float mean[4], rstd[4];
    #pragma unroll
    for (int j = 0; j < 4; ++j) {
        mean[j] = s1[j] * (1.f / 128.f);
        float var = s2[j] * (1.f / 128.f) - mean[j] * mean[j];
        rstd[j] = rsqrtf(var + 1e-5f);
    }
    #pragma unroll
    for (int nt = 0; nt < 8; ++nt) {
        int col = nt * 16 + l15;
        float g = ln_g[col], lb = ln_b[col];
        #pragma unroll
        for (int j = 0; j < 4; ++j) {
            int row = r0 + lk * 4 + j;
            if (row < ndst)
                out[(size_t)row * 128 + col] = (ck[nt][j] - mean[j]) * rstd[j] * g + lb;
        }
    }
}

extern "C" void kernel_launch(void* const* d_in, const int* in_sizes, int n_in,
                              void* d_out, int out_size, void* d_ws, size_t ws_size,
                              hipStream_t stream) {
    const float* h      = (const float*)d_in[0];
    const float* dt     = (const float*)d_in[1];
    const float* ef     = (const float*)d_in[2];
    const float* time_w = (const float*)d_in[3];
    const float* time_b = (const float*)d_in[4];
    const float* wq_w   = (const float*)d_in[5];
    const float* wq_b   = (const float*)d_in[6];
    const float* wk_w   = (const float*)d_in[7];
    const float* wk_b   = (const float*)d_in[8];
    const float* wv_w   = (const float*)d_in[9];
    const float* wv_b   = (const float*)d_in[10];
    const float* wo_w   = (const float*)d_in[11];
    const float* wo_b   = (const float*)d_in[12];
    const float* ln_g   = (const float*)d_in[13];
    const float* ln_b   = (const float*)d_in[14];
    const int* nbr      = (const int*)d_in[15];
    const int* edst     = (const int*)d_in[16];

    int E    = in_sizes[1];
    int ndst = out_size / 128;
    int nblk = (ndst + 255) / 256;
    int ntiles = (E + 127) / 128;

    char* wsb = (char*)d_ws;
    float* qbias = (float*)wsb;                 wsb += 512;
    float* Q     = (float*)wsb;                 wsb += (size_t)ndst * 128 * 4;
    unsigned short* agg16 = (unsigned short*)wsb; wsb += (size_t)ndst * 128 * 2;
    unsigned short* wkT  = (unsigned short*)wsb; wsb += 32768 * 2;
    unsigned short* wvT  = (unsigned short*)wsb; wsb += 32768 * 2;
    unsigned short* woT  = (unsigned short*)wsb; wsb += 32768 * 2;
    unsigned short* wqhT = (unsigned short*)wsb; wsb += 16384 * 2;
    unsigned short* wqlT = (unsigned short*)wsb; wsb += 16384 * 2;
    int* cnt    = (int*)wsb;                    wsb += (size_t)ndst * 4;
    int* fill   = (int*)wsb;                    wsb += (size_t)ndst * 4;
    int* rs     = (int*)wsb;                    wsb += (size_t)ndst * 4;
    int* bsum   = (int*)wsb;                    wsb += 1024;
    int* epos   = (int*)wsb;                    wsb += (size_t)E * 4;
    float2* att2 = (float2*)wsb;                wsb += (size_t)E * 8;
    unsigned short* Vbuf = (unsigned short*)wsb; wsb += (size_t)E * 128 * 2;

    hipMemsetAsync(cnt, 0, (size_t)ndst * 8, stream);  // cnt + fill (adjacent)
    k_pack<<<128, 256, 0, stream>>>(wkT, wvT, woT, wqhT, wqlT, qbias,
                                    wk_w, wv_w, wo_w, wq_w, wq_b, time_b);
    k_count<<<(E + 255) / 256, 256, 0, stream>>>(edst, cnt, E);
    k_scan1<<<nblk, 256, 0, stream>>>(cnt, rs, bsum, ndst);
    k_scan2<<<1, 256, 0, stream>>>(bsum, nblk);
    k_scatter<<<(E + 255) / 256, 256, 0, stream>>>(edst, rs, bsum, fill, epos, E);
    k_q<<<(ndst + 127) / 128, 512, 0, stream>>>(Q, h, wqhT, wqlT, qbias, ndst);
    k_kvA<<<256, 512, 0, stream>>>(h, nbr, edst, dt, ef, time_w, time_b,
                                   wkT, wvT, wk_b, Q, epos, Vbuf, att2,
                                   ndst, E, ntiles);
    k_agg<<<(ndst + 3) / 4, 256, 0, stream>>>(Vbuf, att2, rs, bsum, cnt, wv_b, agg16, ndst);
    k_out<<<(ndst + 127) / 128, 512, 0, stream>>>(agg16, h, woT, wo_b, ln_g, ln_b,
                                                  (float*)d_out, ndst);
}

// Round 15
// 227.987 us; speedup vs baseline: 3.7026x; 2.9072x over previous
//
#include <hip/hip_runtime.h>
#include <hip/hip_bf16.h>
#include <math.h>

// TemporalTransformerConv (TGAT-like) for MI355X — round 15 (consolidation).
// k_kvA = round-10's verified 256-thr 4-phase LDS-staged kernel (126 us).
// k_q/k_out = round-11's 512-thr single-stage MFMA kernels. agg in bf16.
// Persistent/1024-thr variants (r12-r14) all lost to VGPR spills or
// barrier-free-but-low-occupancy effects; reverted.

using bf16 = __hip_bfloat16;
typedef __attribute__((ext_vector_type(8))) short short8;
typedef __attribute__((ext_vector_type(4))) float f32x4;

static __device__ __forceinline__ unsigned short bf16_bits(float x) {
    bf16 h = __float2bfloat16(x);
    unsigned short b;
    __builtin_memcpy(&b, &h, 2);
    return b;
}
static __device__ __forceinline__ unsigned pk2(float x, float y) {
    return (unsigned)bf16_bits(x) | ((unsigned)bf16_bits(y) << 16);
}
static __device__ __forceinline__ float bflo(unsigned u) {
    return __uint_as_float(u << 16);
}
static __device__ __forceinline__ float bfhi(unsigned u) {
    return __uint_as_float(u & 0xffff0000u);
}
union frag_u { short8 s; unsigned u[4]; };

// ------------------------- pack (+ qbias prep) -------------------------
__global__ void k_pack(unsigned short* wkT, unsigned short* wvT, unsigned short* woT,
                       unsigned short* wqhT, unsigned short* wqlT, float* qbias,
                       const float* __restrict__ wk_w, const float* __restrict__ wv_w,
                       const float* __restrict__ wo_w, const float* __restrict__ wq_w,
                       const float* __restrict__ wq_b, const float* __restrict__ time_b) {
    int idx = blockIdx.x * blockDim.x + threadIdx.x;  // 32768
    if (idx < 32768) {
        int n = idx >> 8, k = idx & 255;
        wkT[idx] = bf16_bits(wk_w[(size_t)k * 128 + n]);
        wvT[idx] = bf16_bits(wv_w[(size_t)k * 128 + n]);
        woT[idx] = bf16_bits(wo_w[(size_t)k * 128 + n]);
        if (idx < 16384) {
            int n2 = idx >> 7, k2 = idx & 127;
            float v = wq_w[(size_t)k2 * 128 + n2];
            unsigned short hb = bf16_bits(v);
            wqhT[idx] = hb;
            wqlT[idx] = bf16_bits(v - __uint_as_float((unsigned)hb << 16));
        }
        if (idx < 128) {
            float s = wq_b[idx];
            for (int j = 0; j < 64; ++j)
                s += cosf(time_b[j]) * wq_w[(128 + j) * 128 + idx];
            qbias[idx] = s;
        }
    }
}

// ------------------------- CSR slot assignment -------------------------
__global__ void k_count(const int* __restrict__ edst, int* cnt, int E) {
    int e = blockIdx.x * 256 + threadIdx.x;
    if (e < E) atomicAdd(&cnt[edst[e]], 1);
}

__global__ void k_scan1(const int* __restrict__ cnt, int* rs, int* bsum, int n) {
    __shared__ int s[256];
    int t = threadIdx.x;
    int i = blockIdx.x * 256 + t;
    int v = (i < n) ? cnt[i] : 0;
    s[t] = v;
    __syncthreads();
    for (int off = 1; off < 256; off <<= 1) {
        int x = (t >= off) ? s[t - off] : 0;
        __syncthreads();
        s[t] += x;
        __syncthreads();
    }
    if (i < n) rs[i] = s[t] - v;
    if (t == 255) bsum[blockIdx.x] = s[255];
}

__global__ void k_scan2(int* bsum, int nblk) {
    __shared__ int s[256];
    int t = threadIdx.x;
    int v = (t < nblk) ? bsum[t] : 0;
    s[t] = v;
    __syncthreads();
    for (int off = 1; off < 256; off <<= 1) {
        int x = (t >= off) ? s[t - off] : 0;
        __syncthreads();
        s[t] += x;
        __syncthreads();
    }
    if (t < nblk) bsum[t] = s[t] - v;
}

__global__ void k_scatter(const int* __restrict__ edst, const int* __restrict__ rs,
                          const int* __restrict__ bsum, int* fill, int* epos, int E) {
    int e = blockIdx.x * 256 + threadIdx.x;
    if (e < E) {
        int d = edst[e];
        epos[e] = rs[d] + bsum[d >> 8] + atomicAdd(&fill[d], 1);
    }
}

// ------------------------- Q projection (split-bf16 MFMA, 512 thr) -------------------------
__global__ __launch_bounds__(512) void k_q(
    float* __restrict__ Q, const float* __restrict__ h,
    const unsigned short* __restrict__ wqhT, const unsigned short* __restrict__ wqlT,
    const float* __restrict__ qbias, int ndst)
{
    __shared__ unsigned short Bs[32768];  // Whi [0,16384), Wlo [16384,32768)
    int tid = threadIdx.x;
    int lane = tid & 63, l15 = lane & 15, lk = lane >> 4;
    int r0 = blockIdx.x * 128 + (tid >> 6) * 16;
    int ra = r0 + l15;
    int rc = (ra < ndst) ? ra : (ndst - 1);
    const float* hrow = h + (size_t)rc * 128;

    float4 hx[4][2];
    #pragma unroll
    for (int kk = 0; kk < 4; ++kk) {
        int c0 = kk * 32 + lk * 8;
        hx[kk][0] = *reinterpret_cast<const float4*>(hrow + c0);
        hx[kk][1] = *reinterpret_cast<const float4*>(hrow + c0 + 4);
    }

    #pragma unroll
    for (int it = 0; it < 4; ++it) {
        int i = it * 512 + tid;
        int row = i >> 4, c = i & 15;
        int sw = row * 128 + ((c ^ (row & 15)) << 3);
        *reinterpret_cast<uint4*>(Bs + sw) =
            *reinterpret_cast<const uint4*>(wqhT + (size_t)row * 128 + c * 8);
        *reinterpret_cast<uint4*>(Bs + 16384 + sw) =
            *reinterpret_cast<const uint4*>(wqlT + (size_t)row * 128 + c * 8);
    }

    frag_u ah[4], al[4];
    #pragma unroll
    for (int kk = 0; kk < 4; ++kk) {
        float xs[8] = {hx[kk][0].x, hx[kk][0].y, hx[kk][0].z, hx[kk][0].w,
                       hx[kk][1].x, hx[kk][1].y, hx[kk][1].z, hx[kk][1].w};
        unsigned short hb[8];
        float lo[8];
        #pragma unroll
        for (int t = 0; t < 8; ++t) {
            hb[t] = bf16_bits(xs[t]);
            lo[t] = xs[t] - __uint_as_float((unsigned)hb[t] << 16);
        }
        #pragma unroll
        for (int t = 0; t < 4; ++t)
            ah[kk].u[t] = (unsigned)hb[2*t] | ((unsigned)hb[2*t+1] << 16);
        al[kk].u[0] = pk2(lo[0], lo[1]); al[kk].u[1] = pk2(lo[2], lo[3]);
        al[kk].u[2] = pk2(lo[4], lo[5]); al[kk].u[3] = pk2(lo[6], lo[7]);
    }

    f32x4 ck[8];
    #pragma unroll
    for (int nt = 0; nt < 8; ++nt) ck[nt] = (f32x4){0.f, 0.f, 0.f, 0.f};

    __syncthreads();
    #pragma unroll
    for (int kk2 = 0; kk2 < 4; ++kk2) {
        int co = ((kk2 * 4 + lk) ^ l15) << 3;
        #pragma unroll
        for (int nt = 0; nt < 8; ++nt) {
            int ro = (nt * 16 + l15) * 128;
            short8 bh = *reinterpret_cast<const short8*>(Bs + ro + co);
            short8 bl = *reinterpret_cast<const short8*>(Bs + 16384 + ro + co);
            ck[nt] = __builtin_amdgcn_mfma_f32_16x16x32_bf16(ah[kk2].s, bh, ck[nt], 0, 0, 0);
            ck[nt] = __builtin_amdgcn_mfma_f32_16x16x32_bf16(al[kk2].s, bh, ck[nt], 0, 0, 0);
            ck[nt] = __builtin_amdgcn_mfma_f32_16x16x32_bf16(ah[kk2].s, bl, ck[nt], 0, 0, 0);
        }
    }

    #pragma unroll
    for (int nt = 0; nt < 8; ++nt) {
        int col = nt * 16 + l15;
        float qb = qbias[col];
        #pragma unroll
        for (int j = 0; j < 4; ++j) {
            int row = r0 + lk * 4 + j;
            if (row < ndst) Q[(size_t)row * 128 + col] = ck[nt][j] + qb;
        }
    }
}

// ------------------------- edge pass (round-10 verified: 256 thr, 4-phase LDS) -------------------------
__global__ __launch_bounds__(256) void k_kvA(
    const float* __restrict__ h, const int* __restrict__ nbr, const int* __restrict__ edst,
    const float* __restrict__ dt, const float* __restrict__ ef,
    const float* __restrict__ time_w, const float* __restrict__ time_b,
    const unsigned short* __restrict__ wkT, const unsigned short* __restrict__ wvT,
    const float* __restrict__ wk_b, const float* __restrict__ Q,
    const int* __restrict__ epos,
    unsigned short* __restrict__ Vbuf, float2* __restrict__ att2, int ndst, int E)
{
    __shared__ unsigned short Bs[16384];  // 32 KB
    int tid  = threadIdx.x;
    int lane = tid & 63;
    int l15  = lane & 15;
    int lk   = lane >> 4;
    int e0   = blockIdx.x * 64 + (tid >> 6) * 16;

    int  ea = e0 + l15;
    bool va = ea < E;
    int  na = va ? nbr[ea] : 0;
    float da = va ? dt[ea] : 0.f;
    const float* hrow = h + (size_t)(ndst + na) * 128;
    const float* erow = ef + (size_t)ea * 64;

    int dstr[4], pe[4];
    bool evv[4];
    #pragma unroll
    for (int j = 0; j < 4; ++j) {
        int ed = e0 + lk * 4 + j;
        evv[j]  = ed < E;
        dstr[j] = evv[j] ? edst[ed] : 0;
        pe[j]   = evv[j] ? epos[ed] : 0;
    }

    float4 hx[4][2], ex_[2][2];
    const float4 z4 = make_float4(0.f, 0.f, 0.f, 0.f);
    #pragma unroll
    for (int kk = 0; kk < 4; ++kk) {
        int c0 = kk * 32 + lk * 8;
        hx[kk][0] = va ? *reinterpret_cast<const float4*>(hrow + c0)     : z4;
        hx[kk][1] = va ? *reinterpret_cast<const float4*>(hrow + c0 + 4) : z4;
    }
    #pragma unroll
    for (int t = 0; t < 2; ++t) {
        int c = (4 + t) * 32 + lk * 8 - 128;
        ex_[t][0] = va ? *reinterpret_cast<const float4*>(erow + c)     : z4;
        ex_[t][1] = va ? *reinterpret_cast<const float4*>(erow + c + 4) : z4;
    }

    float qg[8][4];
    #pragma unroll
    for (int nt = 0; nt < 8; ++nt) {
        int gc = nt * 16 + l15;
        #pragma unroll
        for (int j = 0; j < 4; ++j)
            qg[nt][j] = Q[(size_t)dstr[j] * 128 + gc];
    }

    #pragma unroll
    for (int it = 0; it < 8; ++it) {
        int i = it * 256 + tid;
        int row = i >> 4, c = i & 15;
        uint4 v = *reinterpret_cast<const uint4*>(wkT + (size_t)row * 256 + c * 8);
        *reinterpret_cast<uint4*>(Bs + row * 128 + ((c ^ (row & 15)) << 3)) = v;
    }

    float tf[16];
    {
        int j0 = lk * 8;
        #pragma unroll
        for (int t = 0; t < 8; ++t) tf[t]     = __cosf(fmaf(da, time_w[j0 + t],      time_b[j0 + t]));
        #pragma unroll
        for (int t = 0; t < 8; ++t) tf[8 + t] = __cosf(fmaf(da, time_w[j0 + 32 + t], time_b[j0 + 32 + t]));
    }

    frag_u a[8];
    #pragma unroll
    for (int kk = 0; kk < 4; ++kk) {
        a[kk].u[0] = pk2(hx[kk][0].x, hx[kk][0].y); a[kk].u[1] = pk2(hx[kk][0].z, hx[kk][0].w);
        a[kk].u[2] = pk2(hx[kk][1].x, hx[kk][1].y); a[kk].u[3] = pk2(hx[kk][1].z, hx[kk][1].w);
    }
    #pragma unroll
    for (int t = 0; t < 2; ++t) {
        a[4+t].u[0] = pk2(ex_[t][0].x, ex_[t][0].y); a[4+t].u[1] = pk2(ex_[t][0].z, ex_[t][0].w);
        a[4+t].u[2] = pk2(ex_[t][1].x, ex_[t][1].y); a[4+t].u[3] = pk2(ex_[t][1].z, ex_[t][1].w);
    }
    a[6].u[0] = pk2(tf[0], tf[1]);  a[6].u[1] = pk2(tf[2], tf[3]);
    a[6].u[2] = pk2(tf[4], tf[5]);  a[6].u[3] = pk2(tf[6], tf[7]);
    a[7].u[0] = pk2(tf[8], tf[9]);  a[7].u[1] = pk2(tf[10], tf[11]);
    a[7].u[2] = pk2(tf[12], tf[13]); a[7].u[3] = pk2(tf[14], tf[15]);

    f32x4 ck[8];
    #pragma unroll
    for (int nt = 0; nt < 8; ++nt) ck[nt] = (f32x4){0.f, 0.f, 0.f, 0.f};

    __syncthreads();
    #pragma unroll
    for (int kk2 = 0; kk2 < 4; ++kk2) {
        int co = ((kk2 * 4 + lk) ^ l15) << 3;
        #pragma unroll
        for (int nt = 0; nt < 8; ++nt) {
            short8 b = *reinterpret_cast<const short8*>(Bs + (nt * 16 + l15) * 128 + co);
            ck[nt] = __builtin_amdgcn_mfma_f32_16x16x32_bf16(a[kk2].s, b, ck[nt], 0, 0, 0);
        }
    }
    __syncthreads();
    #pragma unroll
    for (int it = 0; it < 8; ++it) {
        int i = it * 256 + tid;
        int row = i >> 4, c = i & 15;
        uint4 v = *reinterpret_cast<const uint4*>(wkT + (size_t)row * 256 + 128 + c * 8);
        *reinterpret_cast<uint4*>(Bs + row * 128 + ((c ^ (row & 15)) << 3)) = v;
    }
    __syncthreads();
    #pragma unroll
    for (int kk2 = 0; kk2 < 4; ++kk2) {
        int co = ((kk2 * 4 + lk) ^ l15) << 3;
        #pragma unroll
        for (int nt = 0; nt < 8; ++nt) {
            short8 b = *reinterpret_cast<const short8*>(Bs + (nt * 16 + l15) * 128 + co);
            ck[nt] = __builtin_amdgcn_mfma_f32_16x16x32_bf16(a[4 + kk2].s, b, ck[nt], 0, 0, 0);
        }
    }
    __syncthreads();
    #pragma unroll
    for (int it = 0; it < 8; ++it) {
        int i = it * 256 + tid;
        int row = i >> 4, c = i & 15;
        uint4 v = *reinterpret_cast<const uint4*>(wvT + (size_t)row * 256 + c * 8);
        *reinterpret_cast<uint4*>(Bs + row * 128 + ((c ^ (row & 15)) << 3)) = v;
    }

    float p0[4], p1[4];
    #pragma unroll
    for (int j = 0; j < 4; ++j) { p0[j] = 0.f; p1[j] = 0.f; }
    #pragma unroll
    for (int nt = 0; nt < 8; ++nt) {
        float kb = wk_b[nt * 16 + l15];
        #pragma unroll
        for (int j = 0; j < 4; ++j) {
            float t = (ck[nt][j] + kb) * qg[nt][j];
            if (nt < 4) p0[j] += t; else p1[j] += t;
        }
    }
    #pragma unroll
    for (int m = 1; m <= 8; m <<= 1)
        #pragma unroll
        for (int j = 0; j < 4; ++j) {
            p0[j] += __shfl_xor(p0[j], m, 64);
            p1[j] += __shfl_xor(p1[j], m, 64);
        }
    if (l15 == 0) {
        #pragma unroll
        for (int j = 0; j < 4; ++j)
            if (evv[j]) {
                float r0 = p0[j]; r0 = (r0 >= 0.f) ? r0 : 0.2f * r0;
                float r1 = p1[j]; r1 = (r1 >= 0.f) ? r1 : 0.2f * r1;
                att2[pe[j]] = make_float2(r0, r1);
            }
    }

    f32x4 cv[8];
    #pragma unroll
    for (int nt = 0; nt < 8; ++nt) cv[nt] = (f32x4){0.f, 0.f, 0.f, 0.f};
    __syncthreads();
    #pragma unroll
    for (int kk2 = 0; kk2 < 4; ++kk2) {
        int co = ((kk2 * 4 + lk) ^ l15) << 3;
        #pragma unroll
        for (int nt = 0; nt < 8; ++nt) {
            short8 b = *reinterpret_cast<const short8*>(Bs + (nt * 16 + l15) * 128 + co);
            cv[nt] = __builtin_amdgcn_mfma_f32_16x16x32_bf16(a[kk2].s, b, cv[nt], 0, 0, 0);
        }
    }
    __syncthreads();
    #pragma unroll
    for (int it = 0; it < 8; ++it) {
        int i = it * 256 + tid;
        int row = i >> 4, c = i & 15;
        uint4 v = *reinterpret_cast<const uint4*>(wvT + (size_t)row * 256 + 128 + c * 8);
        *reinterpret_cast<uint4*>(Bs + row * 128 + ((c ^ (row & 15)) << 3)) = v;
    }
    __syncthreads();
    #pragma unroll
    for (int kk2 = 0; kk2 < 4; ++kk2) {
        int co = ((kk2 * 4 + lk) ^ l15) << 3;
        #pragma unroll
        for (int nt = 0; nt < 8; ++nt) {
            short8 b = *reinterpret_cast<const short8*>(Bs + (nt * 16 + l15) * 128 + co);
            cv[nt] = __builtin_amdgcn_mfma_f32_16x16x32_bf16(a[4 + kk2].s, b, cv[nt], 0, 0, 0);
        }
    }

    #pragma unroll
    for (int j = 0; j < 4; ++j)
        if (evv[j]) {
            uint4 val;
            val.x = pk2(cv[0][j], cv[1][j]);
            val.y = pk2(cv[2][j], cv[3][j]);
            val.z = pk2(cv[4][j], cv[5][j]);
            val.w = pk2(cv[6][j], cv[7][j]);
            *reinterpret_cast<uint4*>(Vbuf + (size_t)pe[j] * 128 + l15 * 8) = val;
        }
}

// ------------------------- streaming segment reduction (bf16 out) -------------------------
__global__ __launch_bounds__(256) void k_agg(
    const unsigned short* __restrict__ Vbuf, const float2* __restrict__ att2,
    const int* __restrict__ rs, const int* __restrict__ bsum, const int* __restrict__ cnt,
    const float* __restrict__ wv_b, unsigned short* __restrict__ agg16, int ndst)
{
    int w = threadIdx.x >> 6, lane = threadIdx.x & 63;
    int d = blockIdx.x * 4 + w;
    if (d >= ndst) return;
    int p0 = lane * 2, p1 = p0 + 1;
    int c0 = ((p0 & 7) << 4) + (p0 >> 3);
    int c1 = ((p1 & 7) << 4) + (p1 >> 3);
    bool h0 = (p0 & 4) != 0, h1 = (p1 & 4) != 0;
    int base = rs[d] + bsum[d >> 8], n = cnt[d];
    const unsigned* V32 = reinterpret_cast<const unsigned*>(Vbuf);
    float den0 = 0.f, den1 = 0.f, acc0 = 0.f, acc1 = 0.f;
    int i = 0;
    for (; i + 4 <= n; i += 4) {
        size_t r = (size_t)(base + i);
        float2 a0 = att2[r], a1 = att2[r+1], a2 = att2[r+2], a3 = att2[r+3];
        unsigned w0 = V32[r*64 + lane], w1 = V32[(r+1)*64 + lane];
        unsigned w2 = V32[(r+2)*64 + lane], w3 = V32[(r+3)*64 + lane];
        float e00 = __expf(a0.x), e01 = __expf(a0.y);
        float e10 = __expf(a1.x), e11 = __expf(a1.y);
        float e20 = __expf(a2.x), e21 = __expf(a2.y);
        float e30 = __expf(a3.x), e31 = __expf(a3.y);
        den0 += e00 + e10 + e20 + e30;
        den1 += e01 + e11 + e21 + e31;
        acc0 = fmaf(h0 ? e01 : e00, bflo(w0), acc0);
        acc1 = fmaf(h1 ? e01 : e00, bfhi(w0), acc1);
        acc0 = fmaf(h0 ? e11 : e10, bflo(w1), acc0);
        acc1 = fmaf(h1 ? e11 : e10, bfhi(w1), acc1);
        acc0 = fmaf(h0 ? e21 : e20, bflo(w2), acc0);
        acc1 = fmaf(h1 ? e21 : e20, bfhi(w2), acc1);
        acc0 = fmaf(h0 ? e31 : e30, bflo(w3), acc0);
        acc1 = fmaf(h1 ? e31 : e30, bfhi(w3), acc1);
    }
    for (; i < n; ++i) {
        size_t r = (size_t)(base + i);
        float2 at = att2[r];
        float ex0 = __expf(at.x), ex1 = __expf(at.y);
        den0 += ex0; den1 += ex1;
        unsigned vv = V32[r*64 + lane];
        acc0 = fmaf(h0 ? ex1 : ex0, bflo(vv), acc0);
        acc1 = fmaf(h1 ? ex1 : ex0, bfhi(vv), acc1);
    }
    float o0 = 0.f, o1 = 0.f;
    if (n > 0) {
        o0 = acc0 / (h0 ? den1 : den0) + wv_b[c0];
        o1 = acc1 / (h1 ? den1 : den0) + wv_b[c1];
    }
    agg16[(size_t)d * 128 + c0] = bf16_bits(o0);
    agg16[(size_t)d * 128 + c1] = bf16_bits(o1);
}

// ------------------------- output (bf16 MFMA + ReLU + LayerNorm, 512 thr) -------------------------
__global__ __launch_bounds__(512) void k_out(
    const unsigned short* __restrict__ agg16, const float* __restrict__ h,
    const unsigned short* __restrict__ woT, const float* __restrict__ wo_b,
    const float* __restrict__ ln_g, const float* __restrict__ ln_b,
    float* __restrict__ out, int ndst)
{
    __shared__ unsigned short Bs[32768];  // 64 KB full woT
    int tid = threadIdx.x;
    int lane = tid & 63, l15 = lane & 15, lk = lane >> 4;
    int r0 = blockIdx.x * 128 + (tid >> 6) * 16;
    int ra = r0 + l15;
    int rc = (ra < ndst) ? ra : (ndst - 1);
    const unsigned short* arow = agg16 + (size_t)rc * 128;
    const float* hrow = h + (size_t)rc * 128;

    frag_u aa[4];
    float4 hx[4][2];
    #pragma unroll
    for (int kk = 0; kk < 4; ++kk) {
        int c0 = kk * 32 + lk * 8;
        aa[kk].s = *reinterpret_cast<const short8*>(arow + c0);
        hx[kk][0] = *reinterpret_cast<const float4*>(hrow + c0);
        hx[kk][1] = *reinterpret_cast<const float4*>(hrow + c0 + 4);
    }

    #pragma unroll
    for (int it = 0; it < 8; ++it) {
        int i = it * 512 + tid;
        int row = i >> 5, c = i & 31;
        uint4 v = *reinterpret_cast<const uint4*>(woT + (size_t)row * 256 + c * 8);
        *reinterpret_cast<uint4*>(Bs + row * 256 + ((c ^ (row & 15)) << 3)) = v;
    }

    frag_u ah[4];
    #pragma unroll
    for (int kk = 0; kk < 4; ++kk) {
        ah[kk].u[0] = pk2(hx[kk][0].x, hx[kk][0].y); ah[kk].u[1] = pk2(hx[kk][0].z, hx[kk][0].w);
        ah[kk].u[2] = pk2(hx[kk][1].x, hx[kk][1].y); ah[kk].u[3] = pk2(hx[kk][1].z, hx[kk][1].w);
    }

    f32x4 ck[8];
    #pragma unroll
    for (int nt = 0; nt < 8; ++nt) ck[nt] = (f32x4){0.f, 0.f, 0.f, 0.f};

    __syncthreads();
    #pragma unroll
    for (int kk2 = 0; kk2 < 4; ++kk2) {
        int coA = ((kk2 * 4 + lk) ^ l15) << 3;          // chunks 0..15 (agg half)
        int coH = (((16 + kk2 * 4 + lk)) ^ l15) << 3;   // chunks 16..31 (h half)
        #pragma unroll
        for (int nt = 0; nt < 8; ++nt) {
            int ro = (nt * 16 + l15) * 256;
            short8 bA = *reinterpret_cast<const short8*>(Bs + ro + coA);
            short8 bH = *reinterpret_cast<const short8*>(Bs + ro + coH);
            ck[nt] = __builtin_amdgcn_mfma_f32_16x16x32_bf16(aa[kk2].s, bA, ck[nt], 0, 0, 0);
            ck[nt] = __builtin_amdgcn_mfma_f32_16x16x32_bf16(ah[kk2].s, bH, ck[nt], 0, 0, 0);
        }
    }

    #pragma unroll
    for (int nt = 0; nt < 8; ++nt) {
        float bo = wo_b[nt * 16 + l15];
        #pragma unroll
        for (int j = 0; j < 4; ++j)
            ck[nt][j] = fmaxf(ck[nt][j] + bo, 0.f);
    }
    float s1[4], s2[4];
    #pragma unroll
    for (int j = 0; j < 4; ++j) { s1[j] = 0.f; s2[j] = 0.f; }
    #pragma unroll
    for (int nt = 0; nt < 8; ++nt)
        #pragma unroll
        for (int j = 0; j < 4; ++j) {
            s1[j] += ck[nt][j];
            s2[j] = fmaf(ck[nt][j], ck[nt][j], s2[j]);
        }
    #pragma unroll
    for (int m = 1; m <= 8; m <<= 1)
        #pragma unroll
        for (int j = 0; j < 4; ++j) {
            s1[j] += __shfl_xor(s1[j], m, 64);
            s2[j] += __shfl_xor(s2[j], m, 64);
        }
    float mean[4], rstd[4];
    #pragma unroll
    for (int j = 0; j < 4; ++j) {
        mean[j] = s1[j] * (1.f / 128.f);
        float var = s2[j] * (1.f / 128.f) - mean[j] * mean[j];
        rstd[j] = rsqrtf(var + 1e-5f);
    }
    #pragma unroll
    for (int nt = 0; nt < 8; ++nt) {
        int col = nt * 16 + l15;
        float g = ln_g[col], lb = ln_b[col];
        #pragma unroll
        for (int j = 0; j < 4; ++j) {
            int row = r0 + lk * 4 + j;
            if (row < ndst)
                out[(size_t)row * 128 + col] = (ck[nt][j] - mean[j]) * rstd[j] * g + lb;
        }
    }
}

extern "C" void kernel_launch(void* const* d_in, const int* in_sizes, int n_in,
                              void* d_out, int out_size, void* d_ws, size_t ws_size,
                              hipStream_t stream) {
    const float* h      = (const float*)d_in[0];
    const float* dt     = (const float*)d_in[1];
    const float* ef     = (const float*)d_in[2];
    const float* time_w = (const float*)d_in[3];
    const float* time_b = (const float*)d_in[4];
    const float* wq_w   = (const float*)d_in[5];
    const float* wq_b   = (const float*)d_in[6];
    const float* wk_w   = (const float*)d_in[7];
    const float* wk_b   = (const float*)d_in[8];
    const float* wv_w   = (const float*)d_in[9];
    const float* wv_b   = (const float*)d_in[10];
    const float* wo_w   = (const float*)d_in[11];
    const float* wo_b   = (const float*)d_in[12];
    const float* ln_g   = (const float*)d_in[13];
    const float* ln_b   = (const float*)d_in[14];
    const int* nbr      = (const int*)d_in[15];
    const int* edst     = (const int*)d_in[16];

    int E    = in_sizes[1];
    int ndst = out_size / 128;
    int nblk = (ndst + 255) / 256;

    char* wsb = (char*)d_ws;
    float* qbias = (float*)wsb;                 wsb += 512;
    float* Q     = (float*)wsb;                 wsb += (size_t)ndst * 128 * 4;
    unsigned short* agg16 = (unsigned short*)wsb; wsb += (size_t)ndst * 128 * 2;
    unsigned short* wkT  = (unsigned short*)wsb; wsb += 32768 * 2;
    unsigned short* wvT  = (unsigned short*)wsb; wsb += 32768 * 2;
    unsigned short* woT  = (unsigned short*)wsb; wsb += 32768 * 2;
    unsigned short* wqhT = (unsigned short*)wsb; wsb += 16384 * 2;
    unsigned short* wqlT = (unsigned short*)wsb; wsb += 16384 * 2;
    int* cnt    = (int*)wsb;                    wsb += (size_t)ndst * 4;
    int* fill   = (int*)wsb;                    wsb += (size_t)ndst * 4;
    int* rs     = (int*)wsb;                    wsb += (size_t)ndst * 4;
    int* bsum   = (int*)wsb;                    wsb += 1024;
    int* epos   = (int*)wsb;                    wsb += (size_t)E * 4;
    float2* att2 = (float2*)wsb;                wsb += (size_t)E * 8;
    unsigned short* Vbuf = (unsigned short*)wsb; wsb += (size_t)E * 128 * 2;

    hipMemsetAsync(cnt, 0, (size_t)ndst * 8, stream);  // cnt + fill (adjacent)
    k_pack<<<128, 256, 0, stream>>>(wkT, wvT, woT, wqhT, wqlT, qbias,
                                    wk_w, wv_w, wo_w, wq_w, wq_b, time_b);
    k_count<<<(E + 255) / 256, 256, 0, stream>>>(edst, cnt, E);
    k_scan1<<<nblk, 256, 0, stream>>>(cnt, rs, bsum, ndst);
    k_scan2<<<1, 256, 0, stream>>>(bsum, nblk);
    k_scatter<<<(E + 255) / 256, 256, 0, stream>>>(edst, rs, bsum, fill, epos, E);
    k_q<<<(ndst + 127) / 128, 512, 0, stream>>>(Q, h, wqhT, wqlT, qbias, ndst);
    k_kvA<<<(E + 63) / 64, 256, 0, stream>>>(h, nbr, edst, dt, ef, time_w, time_b,
                                             wkT, wvT, wk_b, Q, epos, Vbuf, att2, ndst, E);
    k_agg<<<(ndst + 3) / 4, 256, 0, stream>>>(Vbuf, att2, rs, bsum, cnt, wv_b, agg16, ndst);
    k_out<<<(ndst + 127) / 128, 512, 0, stream>>>(agg16, h, woT, wo_b, ln_g, ln_b,
                                                  (float*)d_out, ndst);
}